// Round 7
// baseline (263.018 us; speedup 1.0000x reference)
//
#include <hip/hip_runtime.h>
#include <hip/hip_bf16.h>

// QJL with orthogonal projections, MI355X (gfx950).
// out[t] = scale * sum_m sign(K[t]·S[m]) * (Q[t]·S[m]),  t in [0,131072)
//
// R7: kill the call-ABI spill + register famine found in R6.
//  - 4096 wgs x 256 thr, one 32-token tile each.
//  - S -> bf16 hi/lo tables in d_ws, pre-swizzled to fragment order (prep).
//  - a_hi (16 frags, 64 VGPRs) preloaded once, persistent through both loops.
//  - loop1 (C = K·S^T, 3-pass): issue ALL a_lo loads first, run the 64
//    a_hi-MFMAs (covers L2 latency), then the 32 a_lo-MFMAs. Epilogue
//    compresses accC -> sign/ambiguous bitmasks; ambiguous dots resolved in
//    a single-site __forceinline__ bit-scan loop (OpenBLAS sequential fp32
//    FMA chain — reference-exact, verified R5). No function call -> no spill.
//  - loop2 (QP = Q·S^T, 1-pass on a_hi): apply signs, butterfly + LDS
//    cross-wave combine, one store per token.
//  - __launch_bounds__(256,3): 170-VGPR budget for ~165 live.

#define DIM        128
#define NPROJ      256
#define TILE_T     32
#define NWG        4096        // NTOK / TILE_T
#define LDS_STRIDE 136
#define TAU        6.0e-3f
#define SCALE      0.0048957583489668f  // sqrt(pi/2)/256

typedef __attribute__((ext_vector_type(8))) short short8;  // 8 bf16 = 4 VGPRs
typedef __attribute__((ext_vector_type(4))) float f32x4;

static __device__ __forceinline__ unsigned short bf16_rne(float x){
    unsigned int u = __builtin_bit_cast(unsigned int, x);
    u += 0x7FFFu + ((u >> 16) & 1u);
    return (unsigned short)(u >> 16);
}

// Reference-exact sign (verified R5): OpenBLAS sgemm k-chain — sequential
// ascending fp32 FMA. np.sign semantics (0 -> 0).
static __device__ __forceinline__
float ref_sign(const float* __restrict__ Kg, const float* __restrict__ S,
               int tok, int m){
    const float4* kr = (const float4*)(Kg + (size_t)tok * DIM);
    const float4* sr = (const float4*)(S  + (size_t)m   * DIM);
    float acc = 0.f;
#pragma unroll
    for (int i = 0; i < DIM/4; ++i){
        float4 a = kr[i], b = sr[i];
        acc = __builtin_fmaf(a.x, b.x, acc);
        acc = __builtin_fmaf(a.y, b.y, acc);
        acc = __builtin_fmaf(a.z, b.z, acc);
        acc = __builtin_fmaf(a.w, b.w, acc);
    }
    return (acc > 0.f) ? 1.f : ((acc < 0.f) ? -1.f : 0.f);
}

// S -> bf16 hi/lo tables, fragment order:
//   tab[(((wave*4+ks)*4+ms)*64 + lane)*8 + e]
__global__ void prep_s_kernel(const float* __restrict__ S,
                              unsigned short* __restrict__ shi,
                              unsigned short* __restrict__ slo){
    int t    = blockIdx.x * 256 + threadIdx.x;   // 4096 threads
    int lane = t & 63;
    int ms   = (t >> 6) & 3;
    int ks   = (t >> 8) & 3;
    int g    = (t >> 10) & 3;
    int m    = g*64 + ms*16 + (lane & 15);
    int d    = ks*32 + (lane >> 4)*8;
    const float4* p = (const float4*)(S + (size_t)m*DIM + d);
    float4 x0 = p[0], x1 = p[1];
    float xs[8] = {x0.x,x0.y,x0.z,x0.w, x1.x,x1.y,x1.z,x1.w};
    size_t base = ((size_t)t) * 8;
    unsigned long long h0=0,h1=0,l0=0,l1=0;
#pragma unroll
    for (int e = 0; e < 4; ++e){
        unsigned short hb = bf16_rne(xs[e]);
        float hf = __builtin_bit_cast(float, (unsigned int)hb << 16);
        h0 |= (unsigned long long)hb                    << (16*e);
        l0 |= (unsigned long long)bf16_rne(xs[e] - hf)  << (16*e);
    }
#pragma unroll
    for (int e = 0; e < 4; ++e){
        unsigned short hb = bf16_rne(xs[4+e]);
        float hf = __builtin_bit_cast(float, (unsigned int)hb << 16);
        h1 |= (unsigned long long)hb                      << (16*e);
        l1 |= (unsigned long long)bf16_rne(xs[4+e] - hf)  << (16*e);
    }
    *(unsigned long long*)(shi + base)     = h0;
    *(unsigned long long*)(shi + base + 4) = h1;
    *(unsigned long long*)(slo + base)     = l0;
    *(unsigned long long*)(slo + base + 4) = l1;
}

template<bool USE_TAB>
__global__ __launch_bounds__(256, 3)
void qjl_kernel(const float* __restrict__ Qg, const float* __restrict__ Kg,
                const float* __restrict__ S,
                const unsigned short* __restrict__ shi_tab,
                const unsigned short* __restrict__ slo_tab,
                float* __restrict__ out)
{
    __shared__ unsigned short khi[TILE_T * LDS_STRIDE];
    __shared__ unsigned short klo[TILE_T * LDS_STRIDE];
    __shared__ unsigned short qhi[TILE_T * LDS_STRIDE];
    __shared__ float red[4][TILE_T];

    const int tid  = threadIdx.x;
    const int wave = tid >> 6;
    const int lane = tid & 63;
    const int l16  = lane & 15;
    const int quad = lane >> 4;
    const int tok0 = blockIdx.x * TILE_T;

    // ---- issue K/Q global loads (longest latency first) ----
    const float4* ksrc = (const float4*)(Kg + (size_t)tok0 * DIM);
    const float4* qsrc = (const float4*)(Qg + (size_t)tok0 * DIM);
    float4 kv[4], qv[4];
#pragma unroll
    for (int j = 0; j < 4; ++j){ kv[j] = ksrc[tid + j*256]; qv[j] = qsrc[tid + j*256]; }

    // ---- preload a_hi (persistent, 64 VGPRs) ----
    short8 a_hi[4][4];   // [ks][ms]
    if (USE_TAB){
#pragma unroll
        for (int ks = 0; ks < 4; ++ks)
#pragma unroll
            for (int ms = 0; ms < 4; ++ms)
                a_hi[ks][ms] = *(const short8*)(shi_tab +
                    ((size_t)((wave*4 + ks)*4 + ms)*64 + lane)*8);
    } else {
#pragma unroll
        for (int ks = 0; ks < 4; ++ks)
#pragma unroll
            for (int ms = 0; ms < 4; ++ms){
                const float4* p = (const float4*)(S + (size_t)(wave*64 + ms*16 + l16)*DIM
                                                  + ks*32 + quad*8);
                float4 x0 = p[0], x1 = p[1];
                float xs[8] = {x0.x,x0.y,x0.z,x0.w, x1.x,x1.y,x1.z,x1.w};
                short8 h;
#pragma unroll
                for (int e = 0; e < 8; ++e) h[e] = (short)bf16_rne(xs[e]);
                a_hi[ks][ms] = h;
            }
    }

    // ---- stage K/Q fp32 -> bf16 hi/lo into LDS ----
#pragma unroll
    for (int j = 0; j < 4; ++j){
        int i   = tid + j*256;
        int row = i >> 5;
        int c   = i & 31;
        float kx[4] = {kv[j].x, kv[j].y, kv[j].z, kv[j].w};
        float qx[4] = {qv[j].x, qv[j].y, qv[j].z, qv[j].w};
        unsigned long long hp = 0, lp = 0, qp = 0;
#pragma unroll
        for (int e = 0; e < 4; ++e){
            unsigned short hb = bf16_rne(kx[e]);
            float hf = __builtin_bit_cast(float, (unsigned int)hb << 16);
            hp |= (unsigned long long)hb                   << (16*e);
            lp |= (unsigned long long)bf16_rne(kx[e] - hf) << (16*e);
            qp |= (unsigned long long)bf16_rne(qx[e])      << (16*e);
        }
        int base = row * LDS_STRIDE + c*4;
        *(unsigned long long*)(khi + base) = hp;
        *(unsigned long long*)(klo + base) = lp;
        *(unsigned long long*)(qhi + base) = qp;
    }
    __syncthreads();

    // ---- loop1: C = K·S^T (3-pass), compress to sign masks ----
    // Issue ALL a_lo loads now; a_hi passes below cover the latency.
    short8 a_lo[4][4];
    if (USE_TAB){
#pragma unroll
        for (int ks = 0; ks < 4; ++ks)
#pragma unroll
            for (int ms = 0; ms < 4; ++ms)
                a_lo[ks][ms] = *(const short8*)(slo_tab +
                    ((size_t)((wave*4 + ks)*4 + ms)*64 + lane)*8);
    } else {
#pragma unroll
        for (int ks = 0; ks < 4; ++ks)
#pragma unroll
            for (int ms = 0; ms < 4; ++ms){
                const float4* p = (const float4*)(S + (size_t)(wave*64 + ms*16 + l16)*DIM
                                                  + ks*32 + quad*8);
                float4 x0 = p[0], x1 = p[1];
                float xs[8] = {x0.x,x0.y,x0.z,x0.w, x1.x,x1.y,x1.z,x1.w};
                short8 l;
#pragma unroll
                for (int e = 0; e < 8; ++e){
                    unsigned short hb = bf16_rne(xs[e]);
                    float hf = __builtin_bit_cast(float, (unsigned int)hb << 16);
                    l[e] = (short)bf16_rne(xs[e] - hf);
                }
                a_lo[ks][ms] = l;
            }
    }

    unsigned int negw = 0, zerow = 0;
#pragma unroll
    for (int ts = 0; ts < 2; ++ts){
        f32x4 accC[4];
#pragma unroll
        for (int ms = 0; ms < 4; ++ms) accC[ms] = (f32x4){0.f,0.f,0.f,0.f};

        // a_hi passes: a_hi x khi, a_hi x klo  (no dependence on a_lo loads)
#pragma unroll
        for (int ks = 0; ks < 4; ++ks){
            const int off = (ts*16 + l16) * LDS_STRIDE + ks*32 + quad*8;
            short8 bk = *(const short8*)(khi + off);
            short8 bl = *(const short8*)(klo + off);
#pragma unroll
            for (int ms = 0; ms < 4; ++ms){
                accC[ms] = __builtin_amdgcn_mfma_f32_16x16x32_bf16(a_hi[ks][ms], bk, accC[ms], 0,0,0);
                accC[ms] = __builtin_amdgcn_mfma_f32_16x16x32_bf16(a_hi[ks][ms], bl, accC[ms], 0,0,0);
            }
        }
        // a_lo pass: a_lo x khi (loads have had ~128 MFMAs of cover)
#pragma unroll
        for (int ks = 0; ks < 4; ++ks){
            const int off = (ts*16 + l16) * LDS_STRIDE + ks*32 + quad*8;
            short8 bk = *(const short8*)(khi + off);
#pragma unroll
            for (int ms = 0; ms < 4; ++ms)
                accC[ms] = __builtin_amdgcn_mfma_f32_16x16x32_bf16(a_lo[ks][ms], bk, accC[ms], 0,0,0);
        }

        // epilogue pass 1: consume accC into provisional masks (accC dies here)
        unsigned int ambw = 0;
#pragma unroll
        for (int ms = 0; ms < 4; ++ms){
#pragma unroll
            for (int r = 0; r < 4; ++r){
                float c = accC[ms][r];
                int bit = ms*4 + r;
                if (c < 0.f) negw |= (1u << (ts*16 + bit));
                if (__builtin_fabsf(c) < TAU) ambw |= (1u << bit);
            }
        }
        // epilogue pass 2: rare bit-scan arbitration, single inlined site
        while (ambw){
            int b = __builtin_ctz(ambw);
            ambw &= ambw - 1;
            int ms = (b >> 2) & 3, r = b & 3;
            float s = ref_sign(Kg, S, tok0 + ts*16 + l16,
                               wave*64 + ms*16 + quad*4 + r);
            unsigned int gb = 1u << (ts*16 + b);
            if (s < 0.f) negw |= gb; else negw &= ~gb;
            if (s == 0.f) zerow |= gb;
        }
    }

    // ---- loop2: QP = Q·S^T (1-pass on persistent a_hi), apply signs ----
    float part0 = 0.f, part1 = 0.f;
#pragma unroll
    for (int ts = 0; ts < 2; ++ts){
        f32x4 accQ[4];
#pragma unroll
        for (int ms = 0; ms < 4; ++ms) accQ[ms] = (f32x4){0.f,0.f,0.f,0.f};
#pragma unroll
        for (int ks = 0; ks < 4; ++ks){
            const int off = (ts*16 + l16) * LDS_STRIDE + ks*32 + quad*8;
            short8 bq = *(const short8*)(qhi + off);
#pragma unroll
            for (int ms = 0; ms < 4; ++ms)
                accQ[ms] = __builtin_amdgcn_mfma_f32_16x16x32_bf16(a_hi[ks][ms], bq, accQ[ms], 0,0,0);
        }
#pragma unroll
        for (int ms = 0; ms < 4; ++ms){
#pragma unroll
            for (int r = 0; r < 4; ++r){
                float qp = accQ[ms][r];
                unsigned int gb = ts*16 + ms*4 + r;
                float sv = (zerow >> gb) & 1u ? 0.f
                         : ((negw >> gb) & 1u ? -qp : qp);
                if (ts) part1 += sv; else part0 += sv;
            }
        }
    }

    // ---- reduce: token t in lanes {l16, l16+16, l16+32, l16+48} ----
    part0 += __shfl_xor(part0, 16, 64);
    part0 += __shfl_xor(part0, 32, 64);
    part1 += __shfl_xor(part1, 16, 64);
    part1 += __shfl_xor(part1, 32, 64);
    if (quad == 0){
        red[wave][l16]      = part0;
        red[wave][16 + l16] = part1;
    }
    __syncthreads();
    if (tid < TILE_T)
        out[tok0 + tid] = SCALE * (red[0][tid] + red[1][tid] + red[2][tid] + red[3][tid]);
}

extern "C" void kernel_launch(void* const* d_in, const int* in_sizes, int n_in,
                              void* d_out, int out_size, void* d_ws, size_t ws_size,
                              hipStream_t stream){
    const float* Qg = (const float*)d_in[0];
    const float* Kg = (const float*)d_in[1];
    const float* S  = (const float*)d_in[2];
    float* out = (float*)d_out;

    const size_t tab_elems = (size_t)NPROJ * DIM;                 // 32768
    const size_t need = 2 * tab_elems * sizeof(unsigned short);   // 128 KiB

    if (d_ws && ws_size >= need){
        unsigned short* shi = (unsigned short*)d_ws;
        unsigned short* slo = shi + tab_elems;
        prep_s_kernel<<<16, 256, 0, stream>>>(S, shi, slo);
        qjl_kernel<true><<<NWG, 256, 0, stream>>>(Qg, Kg, S, shi, slo, out);
    } else {
        qjl_kernel<false><<<NWG, 256, 0, stream>>>(Qg, Kg, S, nullptr, nullptr, out);
    }
}